// Round 13
// baseline (117.310 us; speedup 1.0000x reference)
//
#include <hip/hip_runtime.h>
#include <hip/hip_bf16.h>

typedef __attribute__((ext_vector_type(4))) float  float4v;
typedef __attribute__((ext_vector_type(4))) short  short4v;
typedef __attribute__((ext_vector_type(8))) short  short8v;
typedef __attribute__((ext_vector_type(8))) __bf16 bf16x8;

constexpr int E_NUM = 64;
constexpr int HID   = 64;    // expert hidden
constexpr int DIN   = 1024;
constexpr int DOUT  = 1024;
constexpr int TPE   = 1024;  // tokens per expert = 65536/64

__device__ __forceinline__ short4v cvt4(float4v v) {
  short4v r;
#pragma unroll
  for (int j = 0; j < 4; j++) {
    __bf16 b = (__bf16)v[j];
    r[j] = __builtin_bit_cast(short, b);
  }
  return r;
}
__device__ __forceinline__ ushort cvt1(float f) {
  __bf16 b = (__bf16)f;
  return __builtin_bit_cast(ushort, b);
}

// ---------------------------------------------------------------------------
// Kernel 1 (r12 structure at BK=64 -> 32KB LDS -> 3-4 blocks/CU):
// h[t,0:64] = relu(x[t,:] @ W1[e]^T), h bf16 in ws.
// 512 threads (8 waves), dbuf LDS, 1 barrier/step, 16 K-steps.
// Staging: thread covers 32B of one row per matrix per step (2 float4
// loads + 1 ds_write_b128 each for X and W). 16B-unit XOR swizzle.
// More out-of-phase blocks/CU cover each other's drain phases.
// grid = 64*16 = 1024 blocks.
// ---------------------------------------------------------------------------
__global__ __launch_bounds__(512, 6) void fc1_relu_kernel(
    const float* __restrict__ x, const float* __restrict__ w1,
    ushort* __restrict__ hbuf) {
  constexpr int BM = 64, BK = 64;
  __shared__ ushort Xs[2][BM * BK];   // 2 x 8KB, bf16, XOR-swizzled
  __shared__ ushort Ws[2][HID * BK];  // 2 x 8KB   (32KB total)

  // XCD-bijective swizzle: nwg=1024 (div 8)
  int nwg = (int)gridDim.x;
  int blk = (int)(blockIdx.x & 7) * (nwg >> 3) + (int)(blockIdx.x >> 3);
  int e  = blk >> 4;
  int rb = blk & 15;
  const float* xe = x  + (size_t)(e * TPE + rb * BM) * DIN;
  const float* we = w1 + (size_t)e * HID * DIN;

  int tid  = (int)threadIdx.x;
  int lane = tid & 63;
  int wv   = tid >> 6;

  // staging coords: 8 threads per row, each covers 32B (8 floats) of the
  // row's 256B K-slice. LDS unit (16B) = s8 ^ (row&7).
  int row_s = wv * 8 + (lane >> 3);
  int s8    = lane & 7;
  int ul    = s8 ^ (row_s & 7);
  int lidx  = row_s * BK + ul * 8;    // ushort index of 16B unit

  float4v xlo, xhi, wlo, whi;
  auto LOAD = [&](int kt) {
    const float* px = xe + (size_t)row_s * DIN + kt + s8 * 8;
    const float* pw = we + (size_t)row_s * DIN + kt + s8 * 8;
    xlo = *(const float4v*)(px);
    xhi = *(const float4v*)(px + 4);
    wlo = *(const float4v*)(pw);
    whi = *(const float4v*)(pw + 4);
  };
  auto WRITE = [&](ushort* Xb, ushort* Wb) {
    short4v a0 = cvt4(xlo), a1 = cvt4(xhi);
    short4v b0 = cvt4(wlo), b1 = cvt4(whi);
    short8v xa, wb;
#pragma unroll
    for (int q = 0; q < 4; q++) {
      xa[q] = a0[q]; xa[q + 4] = a1[q];
      wb[q] = b0[q]; wb[q + 4] = b1[q];
    }
    *(short8v*)&Xb[lidx] = xa;
    *(short8v*)&Wb[lidx] = wb;
  };

  // wave -> output sub-tile: mf = wv>>1 (16 rows), nb2 = (wv&1)*2
  int m16 = lane & 15;
  int kg  = (lane >> 4) * 8;
  int mf  = wv >> 1;
  int nb2 = (wv & 1) * 2;
  int ar  = mf * 16 + m16;

  float4v acc[2];
#pragma unroll
  for (int j = 0; j < 2; j++)
#pragma unroll
    for (int q = 0; q < 4; q++) acc[j][q] = 0.f;

  auto MMA = [&](const ushort* Xb, const ushort* Wb) {
#pragma unroll
    for (int kk = 0; kk < BK; kk += 32) {
      int c = (kk + kg) >> 3;            // 16B-unit index [0,8)
      short8v a = *(const short8v*)&Xb[ar * BK + (c ^ (ar & 7)) * 8];
#pragma unroll
      for (int j = 0; j < 2; j++) {
        int br = (nb2 + j) * 16 + m16;
        short8v b = *(const short8v*)&Wb[br * BK + (c ^ (br & 7)) * 8];
        acc[j] = __builtin_amdgcn_mfma_f32_16x16x32_bf16(
            __builtin_bit_cast(bf16x8, a), __builtin_bit_cast(bf16x8, b),
            acc[j], 0, 0, 0);
      }
    }
  };

  // ---- K loop: 16 steps, dbuf, 1 barrier/step (r12-verified invariants) ----
  LOAD(0);
#pragma unroll
  for (int s = 0; s < 16; s++) {
    int buf = s & 1;
    WRITE(Xs[buf], Ws[buf]);         // waits own loads, ds_writes
    __syncthreads();
    if (s < 15) LOAD((s + 1) * BK);  // next tile in flight under MMA
    MMA(Xs[buf], Ws[buf]);
  }

  // ---- epilogue: relu -> LDS (linear, reuse Xs[0]) -> 16B stores ----
  // Xs[0] safe: last read of buf0 = MMA(s=14); the sync inside step 15
  // (after WRITE) guarantees all waves finished MMA(14). MMA(15) reads
  // buf1 (Xs[1]/Ws[1]) only.
  ushort* hs = &Xs[0][0];   // 64x64 bf16 = 8KB
#pragma unroll
  for (int j = 0; j < 2; j++) {
    int col = (nb2 + j) * 16 + m16;
#pragma unroll
    for (int q = 0; q < 4; q++) {
      int row = mf * 16 + ((lane >> 4) << 2) + q;
      hs[row * HID + col] = cvt1(fmaxf(acc[j][q], 0.f));
    }
  }
  __syncthreads();
  size_t rowbase = (size_t)e * TPE + rb * BM;
  int row = tid >> 3, c8 = (tid & 7) * 8;   // 512 x 16B = 8KB
  short8v v = *(const short8v*)&hs[row * HID + c8];
  *(short8v*)(hbuf + (rowbase + row) * HID + c8) = v;
}

// ---------------------------------------------------------------------------
// Kernel 2 (FROZEN from round 10): y = h @ W2^T, K=64 pass; epilogue
// transposes acc through LDS then contiguous 16B/lane NON-TEMPORAL stores
// (y bypasses L3, keeping X resident for fc1).
// grid = 64 experts * 8 * 8 = 4096, 256 threads, 32KB LDS.
// ---------------------------------------------------------------------------
__global__ __launch_bounds__(256) void fc2_kernel(
    const ushort* __restrict__ hbuf, const float* __restrict__ w2,
    float* __restrict__ y) {
  constexpr int BM = 128, BN = 128, K = 64;
  __shared__ __align__(16) ushort smem[BM * K + BN * K];   // 32KB
  ushort* Hs = smem;
  ushort* Ws = smem + BM * K;

  int nwg = (int)gridDim.x;  // 4096, divisible by 8
  int blk = (int)(blockIdx.x & 7) * (nwg >> 3) + (int)(blockIdx.x >> 3);

  int e  = blk >> 6;
  int mb = (blk >> 3) & 7;
  int nb = blk & 7;
  const ushort* he = hbuf + (size_t)(e * TPE + mb * BM) * K;
  const float*  we = w2 + ((size_t)e * DOUT + nb * BN) * K;

  int tid  = (int)threadIdx.x;
  int lane = tid & 63;
  int wv   = tid >> 6;

  // stage H: 128x64 bf16 (1024 chunks of 16B, fully contiguous region)
#pragma unroll
  for (int i = 0; i < 4; i++) {
    int f = tid + i * 256;
    int row = f >> 3, c8 = f & 7;
    short8v v = *(const short8v*)(he + (size_t)row * K + c8 * 8);
    *(short8v*)&Hs[(row * K + c8 * 8) ^ ((row & 7) << 3)] = v;
  }
  // stage W2: 128x64 fp32 -> bf16 (2048 float4 chunks, contiguous region)
#pragma unroll
  for (int i = 0; i < 8; i++) {
    int f = tid + i * 256;
    int row = f >> 4, c4 = f & 15;
    float4v v = *(const float4v*)(we + (size_t)row * K + c4 * 4);
    *(short4v*)&Ws[(row * K + c4 * 4) ^ ((row & 7) << 3)] = cvt4(v);
  }
  __syncthreads();

  float4v acc[2][8];
#pragma unroll
  for (int mf = 0; mf < 2; mf++)
#pragma unroll
    for (int nf = 0; nf < 8; nf++)
#pragma unroll
      for (int j = 0; j < 4; j++) acc[mf][nf][j] = 0.f;

  int kg = (lane >> 4) * 8;
#pragma unroll
  for (int kk = 0; kk < K; kk += 32) {
    int k0 = kk + kg;
    short8v a[2];
#pragma unroll
    for (int mf = 0; mf < 2; mf++) {
      int arr = wv * 32 + mf * 16 + (lane & 15);
      a[mf] = *(const short8v*)&Hs[(arr * K + k0) ^ ((arr & 7) << 3)];
    }
#pragma unroll
    for (int nf = 0; nf < 8; nf++) {
      int br = nf * 16 + (lane & 15);
      short8v b = *(const short8v*)&Ws[(br * K + k0) ^ ((br & 7) << 3)];
#pragma unroll
      for (int mf = 0; mf < 2; mf++)
        acc[mf][nf] = __builtin_amdgcn_mfma_f32_16x16x32_bf16(
            __builtin_bit_cast(bf16x8, a[mf]), __builtin_bit_cast(bf16x8, b),
            acc[mf][nf], 0, 0, 0);
    }
  }

  // epilogue: 2 passes of 64 rows through LDS (Hs/Ws dead) -> NT dwordx4
  float* Yt = (float*)smem;   // 64 x 128 fp32 = 32KB
  size_t rowbase = (size_t)(e * TPE + mb * BM);
  int col0 = nb * BN;
#pragma unroll
  for (int pass = 0; pass < 2; pass++) {
    __syncthreads();   // pass0: Hs/Ws reads done; pass1: prev stores read out
    if ((wv >> 1) == pass) {
      int lrow0 = (wv & 1) * 32;
#pragma unroll
      for (int mf = 0; mf < 2; mf++) {
#pragma unroll
        for (int j = 0; j < 4; j++) {
          int lrow = lrow0 + mf * 16 + ((lane >> 4) << 2) + j;
#pragma unroll
          for (int nf = 0; nf < 8; nf++)
            Yt[lrow * BN + nf * 16 + (lane & 15)] = acc[mf][nf][j];
        }
      }
    }
    __syncthreads();
    // cooperative non-temporal store: 2048 chunks of 16B, 8 per thread
#pragma unroll
    for (int i = 0; i < 8; i++) {
      int idx  = tid + i * 256;
      int lrow = idx >> 5;            // 32 chunks per row (128 floats)
      int c4   = idx & 31;
      float4v v = *(const float4v*)&Yt[lrow * BN + c4 * 4];
      float* dst = y + (rowbase + pass * 64 + lrow) * DOUT + col0 + c4 * 4;
      __builtin_nontemporal_store(v, (float4v*)dst);
    }
  }
}

extern "C" void kernel_launch(void* const* d_in, const int* in_sizes, int n_in,
                              void* d_out, int out_size, void* d_ws, size_t ws_size,
                              hipStream_t stream) {
  const float* x  = (const float*)d_in[0];
  // d_in[1] = fwd_expert_count: equal groups (T/E) by problem construction
  const float* w1 = (const float*)d_in[2];
  const float* w2 = (const float*)d_in[3];
  float* yout = (float*)d_out;
  ushort* hbuf = (ushort*)d_ws;   // T * 64 bf16 = 8.4 MB scratch

  fc1_relu_kernel<<<E_NUM * 16, 512, 0, stream>>>(x, w1, hbuf);
  fc2_kernel<<<E_NUM * 64, 256, 0, stream>>>(hbuf, w2, yout);
}

// Round 14
// 111.118 us; speedup vs baseline: 1.0557x; 1.0557x over previous
//
#include <hip/hip_runtime.h>
#include <hip/hip_bf16.h>

typedef __attribute__((ext_vector_type(4))) float  float4v;
typedef __attribute__((ext_vector_type(4))) short  short4v;
typedef __attribute__((ext_vector_type(8))) short  short8v;
typedef __attribute__((ext_vector_type(8))) __bf16 bf16x8;

constexpr int E_NUM = 64;
constexpr int HID   = 64;    // expert hidden
constexpr int DIN   = 1024;
constexpr int DOUT  = 1024;
constexpr int TPE   = 1024;  // tokens per expert = 65536/64

__device__ __forceinline__ short4v cvt4(float4v v) {
  short4v r;
#pragma unroll
  for (int j = 0; j < 4; j++) {
    __bf16 b = (__bf16)v[j];
    r[j] = __builtin_bit_cast(short, b);
  }
  return r;
}
__device__ __forceinline__ ushort cvt1(float f) {
  __bf16 b = (__bf16)f;
  return __builtin_bit_cast(ushort, b);
}

// ---------------------------------------------------------------------------
// Kernel 1 (REVERT to round-12 optimum: BK=128 -> 64KB LDS -> 2 blocks/CU):
// h[t,0:64] = relu(x[t,:] @ W1[e]^T), h bf16 in ws.
// Staging: row-run loads (each inst: 2 rows x 512B contiguous).
// 512 threads (8 waves), dbuf LDS, 1 barrier/step, 8 K-steps.
// Two out-of-phase blocks per CU cover each other's drain/MMA phases.
// grid = 64*16 = 1024 blocks.
// ---------------------------------------------------------------------------
__global__ __launch_bounds__(512, 4) void fc1_relu_kernel(
    const float* __restrict__ x, const float* __restrict__ w1,
    ushort* __restrict__ hbuf) {
  constexpr int BM = 64, BK = 128;
  __shared__ ushort Xs[2][BM * BK];   // 2 x 16KB, bf16, XOR-swizzled
  __shared__ ushort Ws[2][HID * BK];  // 2 x 16KB   (64KB total)

  // XCD-bijective swizzle: nwg=1024 (div 8)
  int nwg = (int)gridDim.x;
  int blk = (int)(blockIdx.x & 7) * (nwg >> 3) + (int)(blockIdx.x >> 3);
  int e  = blk >> 4;
  int rb = blk & 15;
  const float* xe = x  + (size_t)(e * TPE + rb * BM) * DIN;
  const float* we = w1 + (size_t)e * HID * DIN;

  int tid  = (int)threadIdx.x;
  int lane = tid & 63;
  int wv   = tid >> 6;

  // inst i covers rows {wv*8+2i, wv*8+2i+1}; lane l -> row +(l>>5),
  // col floats (l&31)*4  => 512B contiguous per row per instruction.
  float4v xr[4], wr[4];
  int lrow[4];
  int lcol = (lane & 31) * 4;
#pragma unroll
  for (int i = 0; i < 4; i++) lrow[i] = wv * 8 + 2 * i + (lane >> 5);

  auto LOAD = [&](int kt) {
#pragma unroll
    for (int i = 0; i < 4; i++) {
      xr[i] = *(const float4v*)(xe + (size_t)lrow[i] * DIN + kt + lcol);
      wr[i] = *(const float4v*)(we + (size_t)lrow[i] * DIN + kt + lcol);
    }
  };
  auto WRITE = [&](ushort* Xb, ushort* Wb) {
#pragma unroll
    for (int i = 0; i < 4; i++) {
      int r = lrow[i];
      int idx = (r * BK + lcol) ^ ((r & 7) << 3);   // 16B-unit XOR swizzle
      *(short4v*)&Xb[idx] = cvt4(xr[i]);
      *(short4v*)&Wb[idx] = cvt4(wr[i]);
    }
  };

  // wave -> output sub-tile: mf = wv>>1 (16 rows), nb2 = (wv&1)*2
  int m16 = lane & 15;
  int kg  = (lane >> 4) * 8;
  int mf  = wv >> 1;
  int nb2 = (wv & 1) * 2;
  int ar  = mf * 16 + m16;

  float4v acc[2];
#pragma unroll
  for (int j = 0; j < 2; j++)
#pragma unroll
    for (int q = 0; q < 4; q++) acc[j][q] = 0.f;

  auto MMA = [&](const ushort* Xb, const ushort* Wb) {
#pragma unroll
    for (int kk = 0; kk < BK; kk += 32) {
      int k0 = kk + kg;
      short8v a = *(const short8v*)&Xb[(ar * BK + k0) ^ ((ar & 7) << 3)];
#pragma unroll
      for (int j = 0; j < 2; j++) {
        int br = (nb2 + j) * 16 + m16;
        short8v b = *(const short8v*)&Wb[(br * BK + k0) ^ ((br & 7) << 3)];
        acc[j] = __builtin_amdgcn_mfma_f32_16x16x32_bf16(
            __builtin_bit_cast(bf16x8, a), __builtin_bit_cast(bf16x8, b),
            acc[j], 0, 0, 0);
      }
    }
  };

  // ---- K loop: 8 steps, dbuf, 1 barrier/step ----
  LOAD(0);
#pragma unroll
  for (int s = 0; s < 8; s++) {
    int buf = s & 1;
    WRITE(Xs[buf], Ws[buf]);        // waits its own loads, ds_writes
    __syncthreads();
    if (s < 7) LOAD((s + 1) * BK);  // next tile in flight under MMA
    MMA(Xs[buf], Ws[buf]);
  }

  // ---- epilogue: relu -> LDS (linear, reuse Xs[0]) -> 16B stores ----
  // Xs[0] safe: last read of buf0 = MMA(s=6); sync at s=7 (post-WRITE(7))
  // guarantees all waves finished MMA(6). MMA(7) reads buf1 only.
  ushort* hs = &Xs[0][0];   // 64x64 bf16 = 8KB
#pragma unroll
  for (int j = 0; j < 2; j++) {
    int col = (nb2 + j) * 16 + m16;
#pragma unroll
    for (int q = 0; q < 4; q++) {
      int row = mf * 16 + ((lane >> 4) << 2) + q;
      hs[row * HID + col] = cvt1(fmaxf(acc[j][q], 0.f));
    }
  }
  __syncthreads();
  size_t rowbase = (size_t)e * TPE + rb * BM;
  int row = tid >> 3, c8 = (tid & 7) * 8;   // 512 x 16B = 8KB
  short8v v = *(const short8v*)&hs[row * HID + c8];
  *(short8v*)(hbuf + (rowbase + row) * HID + c8) = v;
}

// ---------------------------------------------------------------------------
// Kernel 2 (FROZEN from round 10): y = h @ W2^T, K=64 pass; epilogue
// transposes acc through LDS then contiguous 16B/lane NON-TEMPORAL stores
// (y bypasses L3, keeping X resident for fc1).
// grid = 64 experts * 8 * 8 = 4096, 256 threads, 32KB LDS.
// ---------------------------------------------------------------------------
__global__ __launch_bounds__(256) void fc2_kernel(
    const ushort* __restrict__ hbuf, const float* __restrict__ w2,
    float* __restrict__ y) {
  constexpr int BM = 128, BN = 128, K = 64;
  __shared__ __align__(16) ushort smem[BM * K + BN * K];   // 32KB
  ushort* Hs = smem;
  ushort* Ws = smem + BM * K;

  int nwg = (int)gridDim.x;  // 4096, divisible by 8
  int blk = (int)(blockIdx.x & 7) * (nwg >> 3) + (int)(blockIdx.x >> 3);

  int e  = blk >> 6;
  int mb = (blk >> 3) & 7;
  int nb = blk & 7;
  const ushort* he = hbuf + (size_t)(e * TPE + mb * BM) * K;
  const float*  we = w2 + ((size_t)e * DOUT + nb * BN) * K;

  int tid  = (int)threadIdx.x;
  int lane = tid & 63;
  int wv   = tid >> 6;

  // stage H: 128x64 bf16 (1024 chunks of 16B, fully contiguous region)
#pragma unroll
  for (int i = 0; i < 4; i++) {
    int f = tid + i * 256;
    int row = f >> 3, c8 = f & 7;
    short8v v = *(const short8v*)(he + (size_t)row * K + c8 * 8);
    *(short8v*)&Hs[(row * K + c8 * 8) ^ ((row & 7) << 3)] = v;
  }
  // stage W2: 128x64 fp32 -> bf16 (2048 float4 chunks, contiguous region)
#pragma unroll
  for (int i = 0; i < 8; i++) {
    int f = tid + i * 256;
    int row = f >> 4, c4 = f & 15;
    float4v v = *(const float4v*)(we + (size_t)row * K + c4 * 4);
    *(short4v*)&Ws[(row * K + c4 * 4) ^ ((row & 7) << 3)] = cvt4(v);
  }
  __syncthreads();

  float4v acc[2][8];
#pragma unroll
  for (int mf = 0; mf < 2; mf++)
#pragma unroll
    for (int nf = 0; nf < 8; nf++)
#pragma unroll
      for (int j = 0; j < 4; j++) acc[mf][nf][j] = 0.f;

  int kg = (lane >> 4) * 8;
#pragma unroll
  for (int kk = 0; kk < K; kk += 32) {
    int k0 = kk + kg;
    short8v a[2];
#pragma unroll
    for (int mf = 0; mf < 2; mf++) {
      int arr = wv * 32 + mf * 16 + (lane & 15);
      a[mf] = *(const short8v*)&Hs[(arr * K + k0) ^ ((arr & 7) << 3)];
    }
#pragma unroll
    for (int nf = 0; nf < 8; nf++) {
      int br = nf * 16 + (lane & 15);
      short8v b = *(const short8v*)&Ws[(br * K + k0) ^ ((br & 7) << 3)];
#pragma unroll
      for (int mf = 0; mf < 2; mf++)
        acc[mf][nf] = __builtin_amdgcn_mfma_f32_16x16x32_bf16(
            __builtin_bit_cast(bf16x8, a[mf]), __builtin_bit_cast(bf16x8, b),
            acc[mf][nf], 0, 0, 0);
    }
  }

  // epilogue: 2 passes of 64 rows through LDS (Hs/Ws dead) -> NT dwordx4
  float* Yt = (float*)smem;   // 64 x 128 fp32 = 32KB
  size_t rowbase = (size_t)(e * TPE + mb * BM);
  int col0 = nb * BN;
#pragma unroll
  for (int pass = 0; pass < 2; pass++) {
    __syncthreads();   // pass0: Hs/Ws reads done; pass1: prev stores read out
    if ((wv >> 1) == pass) {
      int lrow0 = (wv & 1) * 32;
#pragma unroll
      for (int mf = 0; mf < 2; mf++) {
#pragma unroll
        for (int j = 0; j < 4; j++) {
          int lrow = lrow0 + mf * 16 + ((lane >> 4) << 2) + j;
#pragma unroll
          for (int nf = 0; nf < 8; nf++)
            Yt[lrow * BN + nf * 16 + (lane & 15)] = acc[mf][nf][j];
        }
      }
    }
    __syncthreads();
    // cooperative non-temporal store: 2048 chunks of 16B, 8 per thread
#pragma unroll
    for (int i = 0; i < 8; i++) {
      int idx  = tid + i * 256;
      int lrow = idx >> 5;            // 32 chunks per row (128 floats)
      int c4   = idx & 31;
      float4v v = *(const float4v*)&Yt[lrow * BN + c4 * 4];
      float* dst = y + (rowbase + pass * 64 + lrow) * DOUT + col0 + c4 * 4;
      __builtin_nontemporal_store(v, (float4v*)dst);
    }
  }
}

extern "C" void kernel_launch(void* const* d_in, const int* in_sizes, int n_in,
                              void* d_out, int out_size, void* d_ws, size_t ws_size,
                              hipStream_t stream) {
  const float* x  = (const float*)d_in[0];
  // d_in[1] = fwd_expert_count: equal groups (T/E) by problem construction
  const float* w1 = (const float*)d_in[2];
  const float* w2 = (const float*)d_in[3];
  float* yout = (float*)d_out;
  ushort* hbuf = (ushort*)d_ws;   // T * 64 bf16 = 8.4 MB scratch

  fc1_relu_kernel<<<E_NUM * 16, 512, 0, stream>>>(x, w1, hbuf);
  fc2_kernel<<<E_NUM * 64, 256, 0, stream>>>(hbuf, w2, yout);
}